// Round 2
// baseline (2858.614 us; speedup 1.0000x reference)
//
#include <hip/hip_runtime.h>

typedef _Float16 f16;
typedef _Float16 f16x4 __attribute__((ext_vector_type(4)));
typedef _Float16 f16x8 __attribute__((ext_vector_type(8)));
typedef float f32x4 __attribute__((ext_vector_type(4)));

#define LSTM_B 256
#define LSTM_H 1024
#define LSTM_O 512
#define LSTM_T 128
#define GATES 4096

// ---------------- fp32 -> fp16 convert (vectorized) ----------------
__global__ void cvt4_kernel(const float4* __restrict__ src, f16x4* __restrict__ dst, int n4) {
  int i = blockIdx.x * blockDim.x + threadIdx.x;
  int st = gridDim.x * blockDim.x;
  for (; i < n4; i += st) {
    float4 v = src[i];
    f16x4 o; o[0] = (f16)v.x; o[1] = (f16)v.y; o[2] = (f16)v.z; o[3] = (f16)v.w;
    dst[i] = o;
  }
}

// ---------------- pack Whh into fragment-linear f16 layout ----------------
// Wpack[hj][frag][lane][8e], frag = kc*8 + s*4 + wn*2 + nt (128 frags/hj)
// value = Whh[(c>>4)*1024 + hj*16 + (c&15)][kc*64 + s*32 + (lane>>4)*8 + e]
//   where c = wn*32 + nt*16 + (lane&15)
__global__ void pack_whh_kernel(const float* __restrict__ Whh, f16* __restrict__ Wpack) {
  int idx = blockIdx.x * 256 + threadIdx.x;      // 64*128*64 = 524288 threads
  int lane = idx & 63;
  int f = (idx >> 6) & 127;
  int hj = idx >> 13;
  int kc = f >> 3, s = (f >> 2) & 1, wn = (f >> 1) & 1, nt = f & 1;
  int c = wn * 32 + nt * 16 + (lane & 15);
  int row = (c >> 4) * 1024 + hj * 16 + (c & 15);
  int k0 = kc * 64 + s * 32 + (lane >> 4) * 8;
  const float* src = Whh + (size_t)row * LSTM_H + k0;
  float4 v0 = *(const float4*)src;
  float4 v1 = *(const float4*)(src + 4);
  f16x8 o;
  o[0] = (f16)v0.x; o[1] = (f16)v0.y; o[2] = (f16)v0.z; o[3] = (f16)v0.w;
  o[4] = (f16)v1.x; o[5] = (f16)v1.y; o[6] = (f16)v1.z; o[7] = (f16)v1.w;
  *(f16x8*)(Wpack + (size_t)idx * 8) = o;
}

// ---------------- generic C[M,N] = A[MxK] * Bw[NxK]^T + bias ----------------
__global__ __launch_bounds__(256) void gemm_bt_kernel(
    const f16* __restrict__ A, const f16* __restrict__ Bw,
    const float* __restrict__ bias0, const float* __restrict__ bias1,
    float* __restrict__ out, int M, int N, int K, int gn, int xswz)
{
  __shared__ __align__(16) f16 As[64][72];
  __shared__ __align__(16) f16 Bs[64][72];
  int bx = blockIdx.x;
  if (xswz) { int n = gridDim.x; bx = (bx & 7) * (n >> 3) + (bx >> 3); }  // bijective: n%8==0
  int mb = bx / gn;
  int m0 = mb * 64;
  int n0 = (bx - mb * gn) * 64;
  int tid = threadIdx.x;
  int lane = tid & 63, w = tid >> 6;
  int wm = w >> 1, wn = w & 1;
  int sr = tid >> 2, sseg = tid & 3;
  const f16* ga = A  + (size_t)(m0 + sr) * K + sseg * 16;
  const f16* gb = Bw + (size_t)(n0 + sr) * K + sseg * 16;
  f32x4 acc00 = {}, acc01 = {}, acc10 = {}, acc11 = {};
  f16x8 ra0 = *(const f16x8*)ga, ra1 = *(const f16x8*)(ga + 8);
  f16x8 rb0 = *(const f16x8*)gb, rb1 = *(const f16x8*)(gb + 8);
  for (int kc = 0; kc < K; kc += 64) {
    __syncthreads();
    *(f16x8*)&As[sr][sseg * 16]     = ra0;
    *(f16x8*)&As[sr][sseg * 16 + 8] = ra1;
    *(f16x8*)&Bs[sr][sseg * 16]     = rb0;
    *(f16x8*)&Bs[sr][sseg * 16 + 8] = rb1;
    __syncthreads();
    if (kc + 64 < K) {
      ga += 64; gb += 64;
      ra0 = *(const f16x8*)ga; ra1 = *(const f16x8*)(ga + 8);
      rb0 = *(const f16x8*)gb; rb1 = *(const f16x8*)(gb + 8);
    }
    int g = lane >> 4, r = lane & 15;
    #pragma unroll
    for (int s = 0; s < 2; s++) {
      f16x8 a0 = *(const f16x8*)&As[wm * 32      + r][s * 32 + g * 8];
      f16x8 a1 = *(const f16x8*)&As[wm * 32 + 16 + r][s * 32 + g * 8];
      f16x8 b0 = *(const f16x8*)&Bs[wn * 32      + r][s * 32 + g * 8];
      f16x8 b1 = *(const f16x8*)&Bs[wn * 32 + 16 + r][s * 32 + g * 8];
      acc00 = __builtin_amdgcn_mfma_f32_16x16x32_f16(a0, b0, acc00, 0, 0, 0);
      acc01 = __builtin_amdgcn_mfma_f32_16x16x32_f16(a0, b1, acc01, 0, 0, 0);
      acc10 = __builtin_amdgcn_mfma_f32_16x16x32_f16(a1, b0, acc10, 0, 0, 0);
      acc11 = __builtin_amdgcn_mfma_f32_16x16x32_f16(a1, b1, acc11, 0, 0, 0);
    }
  }
  int gq = lane >> 4, rr = lane & 15;
  f32x4 accs[2][2] = {{acc00, acc01}, {acc10, acc11}};
  #pragma unroll
  for (int mt = 0; mt < 2; mt++)
    #pragma unroll
    for (int nt = 0; nt < 2; nt++) {
      int row = m0 + wm * 32 + mt * 16 + gq * 4;
      int col = n0 + wn * 32 + nt * 16 + rr;
      float bv = bias0 ? bias0[col] : 0.f;
      if (bias1) bv += bias1[col];
      #pragma unroll
      for (int j = 0; j < 4; j++)
        out[(size_t)(row + j) * N + col] = accs[mt][nt][j] + bv;
    }
}

// ---------------- persistent LSTM recurrence ----------------
struct GroupBar {
  unsigned int cnt; unsigned int pad0[31];
  unsigned int gen; unsigned int pad1[31];
};

__device__ __forceinline__ void group_barrier(GroupBar* bar, unsigned int nwg) {
  __syncthreads();
  if (threadIdx.x == 0) {
    unsigned int old = __hip_atomic_load(&bar->gen, __ATOMIC_RELAXED, __HIP_MEMORY_SCOPE_AGENT);
    unsigned int a = __hip_atomic_fetch_add(&bar->cnt, 1u, __ATOMIC_ACQ_REL, __HIP_MEMORY_SCOPE_AGENT);
    if (a == nwg - 1u) {
      __hip_atomic_store(&bar->cnt, 0u, __ATOMIC_RELAXED, __HIP_MEMORY_SCOPE_AGENT);
      __hip_atomic_fetch_add(&bar->gen, 1u, __ATOMIC_ACQ_REL, __HIP_MEMORY_SCOPE_AGENT);
    } else {
      while (__hip_atomic_load(&bar->gen, __ATOMIC_ACQUIRE, __HIP_MEMORY_SCOPE_AGENT) == old) {
        __builtin_amdgcn_s_sleep(1);
      }
    }
  }
  __syncthreads();
}

// grid = 256 WGs x 256 thr, cooperative. WG (mb, hj): 64 batches x (4 gates x 16 hid).
// Whh frags resident in 128KB LDS; c + x_proj in registers; 1 group barrier (64 WGs) per step.
__global__ __launch_bounds__(256, 1) void lstm_persist_kernel(
    const f16* __restrict__ Wpack, const float* __restrict__ xp,
    f16* __restrict__ hist, GroupBar* __restrict__ bars)
{
  __shared__ __align__(16) f16 Bres[65536];      // 128 KB resident Whh frags
  __shared__ __align__(16) char smx[16640];      // A dbuf (2x8KB, XOR-swizzled) / gsm overlay

  char* Ab = smx;
  float (*gsm)[65] = (float(*)[65])smx;          // epilogue-only overlay

  const int wg = blockIdx.x;
  const int hj = ((wg & 7) << 3) | ((wg >> 3) & 7);  // XCD k hosts hj in [k*8, k*8+8)
  const int mb = wg >> 6;
  GroupBar* bar = &bars[mb];
  const int m0 = mb * 64;
  const int tid = threadIdx.x;
  const int lane = tid & 63, w = tid >> 6;
  const int wm = w >> 1, wn = w & 1;
  const int g = lane >> 4, r = lane & 15;

  // one-time: Whh fragment strip -> LDS (linear copy)
  {
    const f16x8* src = (const f16x8*)(Wpack + (size_t)hj * 65536);
    f16x8* dst = (f16x8*)Bres;
    for (int i = tid; i < 8192; i += 256) dst[i] = src[i];
  }

  // one-time: per-thread x_proj and c registers
  const int b_loc = tid & 63, hh0 = tid >> 6;
  const size_t rowb = (size_t)(m0 + b_loc);
  const float* xprow = xp + rowb * GATES + hj * 16 + hh0 * 4;
  float4 xi = *(const float4*)(xprow);
  float4 xf = *(const float4*)(xprow + LSTM_H);
  float4 xg = *(const float4*)(xprow + 2 * LSTM_H);
  float4 xo = *(const float4*)(xprow + 3 * LSTM_H);
  float xiv[4] = {xi.x, xi.y, xi.z, xi.w};
  float xfv[4] = {xf.x, xf.y, xf.z, xf.w};
  float xgv[4] = {xg.x, xg.y, xg.z, xg.w};
  float xov[4] = {xo.x, xo.y, xo.z, xo.w};
  float cvv[4] = {0.f, 0.f, 0.f, 0.f};

  // staging geometry
  const int sr = tid >> 2, sseg = tid & 3;
  const int wb0 = sr * 128 + ((sseg * 32)      ^ ((sr & 7) << 4));
  const int wb1 = sr * 128 + ((sseg * 32 + 16) ^ ((sr & 7) << 4));
  // A-frag read offsets (mt, s); rows of a 16-block share (row&7) == (r&7)
  const int xr = (r & 7) << 4;
  const int rb00 = (wm * 32 + r) * 128 + ((g * 16)      ^ xr);
  const int rb01 = (wm * 32 + r) * 128 + ((64 + g * 16) ^ xr);
  const int rb10 = rb00 + 16 * 128;
  const int rb11 = rb01 + 16 * 128;
  // B frag byte offset base: frag = kc*8 + s*4 + wn*2 + nt ; byte = frag*1024 + lane*16
  const int bb = wn * 2048 + lane * 16;

  __syncthreads();   // Bres ready

  for (int t = 0; t < LSTM_T; t++) {
    f32x4 acc00 = {}, acc01 = {}, acc10 = {}, acc11 = {};
    if (t > 0) {
      const f16* ga = hist + (size_t)(t - 1) * (LSTM_B * LSTM_H)
                    + (size_t)(m0 + sr) * LSTM_H + sseg * 16;
      // prologue: chunk0 -> LDS buf0, chunk1 -> regs
      f16x8 ra0 = *(const f16x8*)ga;
      f16x8 ra1 = *(const f16x8*)(ga + 8);
      *(f16x8*)(Ab + wb0) = ra0;
      *(f16x8*)(Ab + wb1) = ra1;
      ra0 = *(const f16x8*)(ga + 64);
      ra1 = *(const f16x8*)(ga + 72);
      __syncthreads();
      #pragma unroll 2
      for (int kc = 0; kc < 16; kc++) {
        const int bo = (kc & 1) * 8192;
        f16x8 rn0 = {}, rn1 = {};
        if (kc + 2 < 16) {              // prefetch chunk kc+2 (hides L2/LLC latency)
          rn0 = *(const f16x8*)(ga + (kc + 2) * 64);
          rn1 = *(const f16x8*)(ga + (kc + 2) * 64 + 8);
        }
        const char* Bb = (const char*)Bres + kc * 8192;
        f16x8 a00 = *(const f16x8*)(Ab + bo + rb00);
        f16x8 a10 = *(const f16x8*)(Ab + bo + rb10);
        f16x8 b00 = *(const f16x8*)(Bb + bb);
        f16x8 b10 = *(const f16x8*)(Bb + bb + 1024);
        acc00 = __builtin_amdgcn_mfma_f32_16x16x32_f16(a00, b00, acc00, 0, 0, 0);
        acc01 = __builtin_amdgcn_mfma_f32_16x16x32_f16(a00, b10, acc01, 0, 0, 0);
        acc10 = __builtin_amdgcn_mfma_f32_16x16x32_f16(a10, b00, acc10, 0, 0, 0);
        acc11 = __builtin_amdgcn_mfma_f32_16x16x32_f16(a10, b10, acc11, 0, 0, 0);
        f16x8 a01 = *(const f16x8*)(Ab + bo + rb01);
        f16x8 a11 = *(const f16x8*)(Ab + bo + rb11);
        f16x8 b01 = *(const f16x8*)(Bb + 4096 + bb);
        f16x8 b11 = *(const f16x8*)(Bb + 4096 + bb + 1024);
        acc00 = __builtin_amdgcn_mfma_f32_16x16x32_f16(a01, b01, acc00, 0, 0, 0);
        acc01 = __builtin_amdgcn_mfma_f32_16x16x32_f16(a01, b11, acc01, 0, 0, 0);
        acc10 = __builtin_amdgcn_mfma_f32_16x16x32_f16(a11, b01, acc10, 0, 0, 0);
        acc11 = __builtin_amdgcn_mfma_f32_16x16x32_f16(a11, b11, acc11, 0, 0, 0);
        if (kc + 1 < 16) {              // stage chunk kc+1 into the other buffer
          *(f16x8*)(Ab + (bo ^ 8192) + wb0) = ra0;
          *(f16x8*)(Ab + (bo ^ 8192) + wb1) = ra1;
          ra0 = rn0; ra1 = rn1;
        }
        __syncthreads();
      }
    }
    // gates tile -> gsm (As reads all done; overlay safe)
    {
      f32x4 accs[2][2] = {{acc00, acc01}, {acc10, acc11}};
      #pragma unroll
      for (int mt = 0; mt < 2; mt++)
        #pragma unroll
        for (int nt = 0; nt < 2; nt++)
          #pragma unroll
          for (int j = 0; j < 4; j++)
            gsm[wm * 32 + mt * 16 + g * 4 + j][wn * 32 + nt * 16 + r] = accs[mt][nt][j];
    }
    __syncthreads();
    // elementwise cell update (c and x_proj live in registers)
    float hnew[4];
    #pragma unroll
    for (int u = 0; u < 4; u++) {
      int hh = hh0 * 4 + u;
      float iv = gsm[b_loc][hh]      + xiv[u];
      float fv = gsm[b_loc][16 + hh] + xfv[u];
      float gv = gsm[b_loc][32 + hh] + xgv[u];
      float ov = gsm[b_loc][48 + hh] + xov[u];
      iv = 1.f / (1.f + __expf(-iv));
      fv = 1.f / (1.f + __expf(-fv));
      gv = 2.f / (1.f + __expf(-2.f * gv)) - 1.f;
      ov = 1.f / (1.f + __expf(-ov));
      float cn = fv * cvv[u] + iv * gv;
      cvv[u] = cn;
      float tc = 2.f / (1.f + __expf(-2.f * cn)) - 1.f;
      hnew[u] = ov * tc;
    }
    f16x4 hw; hw[0] = (f16)hnew[0]; hw[1] = (f16)hnew[1]; hw[2] = (f16)hnew[2]; hw[3] = (f16)hnew[3];
    *(f16x4*)(hist + (size_t)t * (LSTM_B * LSTM_H) + rowb * LSTM_H + hj * 16 + hh0 * 4) = hw;
    group_barrier(bar, 64);   // hist[t] visible to the 64 WGs of this batch-block
  }
}

extern "C" void kernel_launch(void* const* d_in, const int* in_sizes, int n_in,
                              void* d_out, int out_size, void* d_ws, size_t ws_size,
                              hipStream_t stream)
{
  (void)in_sizes; (void)n_in; (void)out_size; (void)ws_size;
  const float* C     = (const float*)d_in[0];
  const float* W_ih  = (const float*)d_in[1];
  const float* W_hh  = (const float*)d_in[2];
  const float* b_ih  = (const float*)d_in[3];
  const float* b_hh  = (const float*)d_in[4];
  const float* W_lin = (const float*)d_in[5];
  const float* b_lin = (const float*)d_in[6];

  char* ws = (char*)d_ws;
  size_t off = 0;
  auto alloc = [&](size_t bytes) { void* p = ws + off; off += (bytes + 255) & ~(size_t)255; return p; };
  f16*      Wih16  = (f16*)alloc((size_t)GATES * LSTM_H * 2);
  f16*      Wlin16 = (f16*)alloc((size_t)LSTM_O * LSTM_H * 2);
  f16*      C16    = (f16*)alloc((size_t)LSTM_B * LSTM_H * 2);
  f16*      Wpack  = (f16*)alloc((size_t)GATES * LSTM_H * 2);
  float*    xp     = (float*)alloc((size_t)LSTM_B * GATES * 4);
  f16*      hist   = (f16*)alloc((size_t)LSTM_T * LSTM_B * LSTM_H * 2);
  GroupBar* bars   = (GroupBar*)alloc(4 * sizeof(GroupBar));

  cvt4_kernel<<<2048, 256, 0, stream>>>((const float4*)W_ih,  (f16x4*)Wih16,  GATES * LSTM_H / 4);
  cvt4_kernel<<<512,  256, 0, stream>>>((const float4*)W_lin, (f16x4*)Wlin16, LSTM_O * LSTM_H / 4);
  cvt4_kernel<<<256,  256, 0, stream>>>((const float4*)C,     (f16x4*)C16,    LSTM_B * LSTM_H / 4);
  pack_whh_kernel<<<2048, 256, 0, stream>>>(W_hh, Wpack);
  hipMemsetAsync(bars, 0, 4 * sizeof(GroupBar), stream);

  // x_proj = C @ W_ih^T + b_ih + b_hh (input constant across time)
  gemm_bt_kernel<<<(LSTM_B / 64) * (GATES / 64), 256, 0, stream>>>(
      C16, Wih16, b_ih, b_hh, xp, LSTM_B, GATES, LSTM_H, GATES / 64, 0);

  // recurrence: one cooperative kernel, all 128 steps
  {
    const f16* wp = Wpack; const float* xpp = xp; f16* hp = hist; GroupBar* bp = bars;
    void* args[] = { (void*)&wp, (void*)&xpp, (void*)&hp, (void*)&bp };
    hipLaunchCooperativeKernel((void*)lstm_persist_kernel, dim3(256), dim3(256), args, 0, stream);
  }

  // ys = hist @ W_lin^T + b_lin, one batched GEMM (XCD-swizzled: 4096 % 8 == 0)
  gemm_bt_kernel<<<(LSTM_T * LSTM_B / 64) * (LSTM_O / 64), 256, 0, stream>>>(
      hist, Wlin16, b_lin, nullptr, (float*)d_out,
      LSTM_T * LSTM_B, LSTM_O, LSTM_H, LSTM_O / 64, 1);
}

// Round 3
// 2324.213 us; speedup vs baseline: 1.2299x; 1.2299x over previous
//
#include <hip/hip_runtime.h>

typedef _Float16 f16;
typedef _Float16 f16x4 __attribute__((ext_vector_type(4)));
typedef _Float16 f16x8 __attribute__((ext_vector_type(8)));
typedef float f32x4 __attribute__((ext_vector_type(4)));

#define LSTM_B 256
#define LSTM_H 1024
#define LSTM_O 512
#define LSTM_T 128
#define GATES 4096

// hist blocked layout: element (t, b, h) at
//   ((t*64 + (h>>4))*4 + (b>>6))*1024 + (b&63)*16 + (h&15)
// -> each producer WG (mb,hj) writes ONE contiguous 2KB block per step
//    (single writer per cacheline; no cross-XCD false sharing).

// ---------------- fp32 -> fp16 convert (vectorized) ----------------
__global__ void cvt4_kernel(const float4* __restrict__ src, f16x4* __restrict__ dst, int n4) {
  int i = blockIdx.x * blockDim.x + threadIdx.x;
  int st = gridDim.x * blockDim.x;
  for (; i < n4; i += st) {
    float4 v = src[i];
    f16x4 o; o[0] = (f16)v.x; o[1] = (f16)v.y; o[2] = (f16)v.z; o[3] = (f16)v.w;
    dst[i] = o;
  }
}

// ---------------- pack Whh into fragment-linear f16 layout ----------------
__global__ void pack_whh_kernel(const float* __restrict__ Whh, f16* __restrict__ Wpack) {
  int idx = blockIdx.x * 256 + threadIdx.x;      // 64*128*64 = 524288 threads
  int lane = idx & 63;
  int f = (idx >> 6) & 127;
  int hj = idx >> 13;
  int kc = f >> 3, s = (f >> 2) & 1, wn = (f >> 1) & 1, nt = f & 1;
  int c = wn * 32 + nt * 16 + (lane & 15);
  int row = (c >> 4) * 1024 + hj * 16 + (c & 15);
  int k0 = kc * 64 + s * 32 + (lane >> 4) * 8;
  const float* src = Whh + (size_t)row * LSTM_H + k0;
  float4 v0 = *(const float4*)src;
  float4 v1 = *(const float4*)(src + 4);
  f16x8 o;
  o[0] = (f16)v0.x; o[1] = (f16)v0.y; o[2] = (f16)v0.z; o[3] = (f16)v0.w;
  o[4] = (f16)v1.x; o[5] = (f16)v1.y; o[6] = (f16)v1.z; o[7] = (f16)v1.w;
  *(f16x8*)(Wpack + (size_t)idx * 8) = o;
}

// ---------------- generic C[M,N] = A[MxK] * Bw[NxK]^T + bias ----------------
// blkA: A is in blocked hist layout (M rows = t*256+b), else row-major MxK.
__global__ __launch_bounds__(256) void gemm_bt_kernel(
    const f16* __restrict__ A, const f16* __restrict__ Bw,
    const float* __restrict__ bias0, const float* __restrict__ bias1,
    float* __restrict__ out, int M, int N, int K, int gn, int xswz, int blkA)
{
  __shared__ __align__(16) f16 As[64][72];
  __shared__ __align__(16) f16 Bs[64][72];
  int bx = blockIdx.x;
  if (xswz) { int n = gridDim.x; bx = (bx & 7) * (n >> 3) + (bx >> 3); }  // bijective: n%8==0
  int mb = bx / gn;
  int m0 = mb * 64;
  int n0 = (bx - mb * gn) * 64;
  int tid = threadIdx.x;
  int lane = tid & 63, w = tid >> 6;
  int wm = w >> 1, wn = w & 1;
  int sr = tid >> 2, sseg = tid & 3;
  const f16* ga;
  size_t kadv;
  if (blkA) {
    int m = m0 + sr;
    ga = A + ((size_t)(m >> 8) * 256 + (size_t)sseg * 4 + ((m >> 6) & 3)) * 1024 + (m & 63) * 16;
    kadv = 16384;
  } else {
    ga = A + (size_t)(m0 + sr) * K + sseg * 16;
    kadv = 64;
  }
  const f16* gb = Bw + (size_t)(n0 + sr) * K + sseg * 16;
  f32x4 acc00 = {}, acc01 = {}, acc10 = {}, acc11 = {};
  f16x8 ra0 = *(const f16x8*)ga, ra1 = *(const f16x8*)(ga + 8);
  f16x8 rb0 = *(const f16x8*)gb, rb1 = *(const f16x8*)(gb + 8);
  for (int kc = 0; kc < K; kc += 64) {
    __syncthreads();
    *(f16x8*)&As[sr][sseg * 16]     = ra0;
    *(f16x8*)&As[sr][sseg * 16 + 8] = ra1;
    *(f16x8*)&Bs[sr][sseg * 16]     = rb0;
    *(f16x8*)&Bs[sr][sseg * 16 + 8] = rb1;
    __syncthreads();
    if (kc + 64 < K) {
      ga += kadv; gb += 64;
      ra0 = *(const f16x8*)ga; ra1 = *(const f16x8*)(ga + 8);
      rb0 = *(const f16x8*)gb; rb1 = *(const f16x8*)(gb + 8);
    }
    int g = lane >> 4, r = lane & 15;
    #pragma unroll
    for (int s = 0; s < 2; s++) {
      f16x8 a0 = *(const f16x8*)&As[wm * 32      + r][s * 32 + g * 8];
      f16x8 a1 = *(const f16x8*)&As[wm * 32 + 16 + r][s * 32 + g * 8];
      f16x8 b0 = *(const f16x8*)&Bs[wn * 32      + r][s * 32 + g * 8];
      f16x8 b1 = *(const f16x8*)&Bs[wn * 32 + 16 + r][s * 32 + g * 8];
      acc00 = __builtin_amdgcn_mfma_f32_16x16x32_f16(a0, b0, acc00, 0, 0, 0);
      acc01 = __builtin_amdgcn_mfma_f32_16x16x32_f16(a0, b1, acc01, 0, 0, 0);
      acc10 = __builtin_amdgcn_mfma_f32_16x16x32_f16(a1, b0, acc10, 0, 0, 0);
      acc11 = __builtin_amdgcn_mfma_f32_16x16x32_f16(a1, b1, acc11, 0, 0, 0);
    }
  }
  int gq = lane >> 4, rr = lane & 15;
  f32x4 accs[2][2] = {{acc00, acc01}, {acc10, acc11}};
  #pragma unroll
  for (int mt = 0; mt < 2; mt++)
    #pragma unroll
    for (int nt = 0; nt < 2; nt++) {
      int row = m0 + wm * 32 + mt * 16 + gq * 4;
      int col = n0 + wn * 32 + nt * 16 + rr;
      float bv = bias0 ? bias0[col] : 0.f;
      if (bias1) bv += bias1[col];
      #pragma unroll
      for (int j = 0; j < 4; j++)
        out[(size_t)(row + j) * N + col] = accs[mt][nt][j] + bv;
    }
}

// ---------------- persistent LSTM recurrence ----------------
// Lean monotonic barrier: one counter per group, released by fence+relaxed add,
// awaited by relaxed spin + one acquire fence. No reset -> no gen race.
__device__ __forceinline__ void group_barrier(unsigned* c, unsigned target) {
  __syncthreads();
  if (threadIdx.x == 0) {
    __builtin_amdgcn_fence(__ATOMIC_RELEASE, "agent");
    __hip_atomic_fetch_add(c, 1u, __ATOMIC_RELAXED, __HIP_MEMORY_SCOPE_AGENT);
    while (__hip_atomic_load(c, __ATOMIC_RELAXED, __HIP_MEMORY_SCOPE_AGENT) < target)
      __builtin_amdgcn_s_sleep(2);
    __builtin_amdgcn_fence(__ATOMIC_ACQUIRE, "agent");
  }
  __syncthreads();
}

// grid = 256 WGs x 256 thr, cooperative. Group = 64 WGs sharing mb, pinned to an
// XCD PAIR (mb = (wg&7)>>1), so all h-exchange + barrier traffic is 2-XCD-local.
__global__ __launch_bounds__(256, 1) void lstm_persist_kernel(
    const f16* __restrict__ Wpack, const float* __restrict__ xp,
    f16* __restrict__ hist, unsigned* __restrict__ bars)
{
  __shared__ __align__(16) f16 Bres[65536];      // 128 KB resident Whh frags
  __shared__ __align__(16) char smx[16640];      // A dbuf (2x8KB, XOR-swizzled) / gsm overlay

  char* Ab = smx;
  float (*gsm)[65] = (float(*)[65])smx;

  const int wg = blockIdx.x;
  const int mb = (wg & 7) >> 1;                        // XCD pair -> batch group
  const int hj = ((wg >> 3) << 1) | (wg & 1);          // 64 hid-slices per group
  unsigned* bar = bars + mb * 64;                      // 256B-padded counters
  const int m0 = mb * 64;
  const int tid = threadIdx.x;
  const int lane = tid & 63, w = tid >> 6;
  const int wm = w >> 1, wn = w & 1;
  const int g = lane >> 4, r = lane & 15;

  // one-time: Whh fragment strip -> LDS
  {
    const f16x8* src = (const f16x8*)(Wpack + (size_t)hj * 65536);
    f16x8* dst = (f16x8*)Bres;
    for (int i = tid; i < 8192; i += 256) dst[i] = src[i];
  }

  // one-time: per-thread x_proj and c registers
  const int b_loc = tid & 63, hh0 = tid >> 6;
  const float* xprow = xp + (size_t)(m0 + b_loc) * GATES + hj * 16 + hh0 * 4;
  float4 xi = *(const float4*)(xprow);
  float4 xf = *(const float4*)(xprow + LSTM_H);
  float4 xg = *(const float4*)(xprow + 2 * LSTM_H);
  float4 xo = *(const float4*)(xprow + 3 * LSTM_H);
  float xiv[4] = {xi.x, xi.y, xi.z, xi.w};
  float xfv[4] = {xf.x, xf.y, xf.z, xf.w};
  float xgv[4] = {xg.x, xg.y, xg.z, xg.w};
  float xov[4] = {xo.x, xo.y, xo.z, xo.w};
  float cvv[4] = {0.f, 0.f, 0.f, 0.f};

  // staging geometry (A tile 64b x 64k, XOR-swizzled rows)
  const int sr = tid >> 2, sseg = tid & 3;
  const int wb0 = sr * 128 + ((sseg * 32)      ^ ((sr & 7) << 4));
  const int wb1 = sr * 128 + ((sseg * 32 + 16) ^ ((sr & 7) << 4));
  const int xr = (r & 7) << 4;
  const int rb00 = (wm * 32 + r) * 128 + ((g * 16)      ^ xr);
  const int rb01 = (wm * 32 + r) * 128 + ((64 + g * 16) ^ xr);
  const int rb10 = rb00 + 16 * 128;
  const int rb11 = rb01 + 16 * 128;
  const int bb = wn * 2048 + lane * 16;
  const int stag = hj >> 2;                            // staggered K-chunk start
  // chunk kc of hprev: tb + kc*16384 (+8 for second half)
  const f16* tb_base = hist + (size_t)sseg * 4096 + (size_t)mb * 1024 + sr * 16;
  // h output block (contiguous 2KB per WG per step)
  f16* hob = hist + ((size_t)hj * 4 + mb) * 1024 + b_loc * 16 + hh0 * 4;

  __syncthreads();   // Bres ready

  for (int t = 0; t < LSTM_T; t++) {
    f32x4 acc00 = {}, acc01 = {}, acc10 = {}, acc11 = {};
    if (t > 0) {
      const f16* tb = tb_base + (size_t)(t - 1) * 262144;
      f16x8 ra0 = *(const f16x8*)(tb + stag * 16384);
      f16x8 ra1 = *(const f16x8*)(tb + stag * 16384 + 8);
      *(f16x8*)(Ab + wb0) = ra0;
      *(f16x8*)(Ab + wb1) = ra1;
      {
        int k1 = (stag + 1) & 15;
        ra0 = *(const f16x8*)(tb + k1 * 16384);
        ra1 = *(const f16x8*)(tb + k1 * 16384 + 8);
      }
      __syncthreads();
      #pragma unroll 2
      for (int i = 0; i < 16; i++) {
        const int bo = (i & 1) * 8192;
        const int kc = (i + stag) & 15;
        f16x8 rn0 = {}, rn1 = {};
        if (i + 2 < 16) {
          int k2 = (i + 2 + stag) & 15;
          rn0 = *(const f16x8*)(tb + k2 * 16384);
          rn1 = *(const f16x8*)(tb + k2 * 16384 + 8);
        }
        const char* Bb = (const char*)Bres + kc * 8192;
        f16x8 a00 = *(const f16x8*)(Ab + bo + rb00);
        f16x8 a10 = *(const f16x8*)(Ab + bo + rb10);
        f16x8 b00 = *(const f16x8*)(Bb + bb);
        f16x8 b10 = *(const f16x8*)(Bb + bb + 1024);
        acc00 = __builtin_amdgcn_mfma_f32_16x16x32_f16(a00, b00, acc00, 0, 0, 0);
        acc01 = __builtin_amdgcn_mfma_f32_16x16x32_f16(a00, b10, acc01, 0, 0, 0);
        acc10 = __builtin_amdgcn_mfma_f32_16x16x32_f16(a10, b00, acc10, 0, 0, 0);
        acc11 = __builtin_amdgcn_mfma_f32_16x16x32_f16(a10, b10, acc11, 0, 0, 0);
        f16x8 a01 = *(const f16x8*)(Ab + bo + rb01);
        f16x8 a11 = *(const f16x8*)(Ab + bo + rb11);
        f16x8 b01 = *(const f16x8*)(Bb + 4096 + bb);
        f16x8 b11 = *(const f16x8*)(Bb + 4096 + bb + 1024);
        acc00 = __builtin_amdgcn_mfma_f32_16x16x32_f16(a01, b01, acc00, 0, 0, 0);
        acc01 = __builtin_amdgcn_mfma_f32_16x16x32_f16(a01, b11, acc01, 0, 0, 0);
        acc10 = __builtin_amdgcn_mfma_f32_16x16x32_f16(a11, b01, acc10, 0, 0, 0);
        acc11 = __builtin_amdgcn_mfma_f32_16x16x32_f16(a11, b11, acc11, 0, 0, 0);
        if (i + 1 < 16) {
          *(f16x8*)(Ab + (bo ^ 8192) + wb0) = ra0;
          *(f16x8*)(Ab + (bo ^ 8192) + wb1) = ra1;
          ra0 = rn0; ra1 = rn1;
        }
        __syncthreads();
      }
    }
    // gates tile -> gsm overlay
    {
      f32x4 accs[2][2] = {{acc00, acc01}, {acc10, acc11}};
      #pragma unroll
      for (int mt = 0; mt < 2; mt++)
        #pragma unroll
        for (int nt = 0; nt < 2; nt++)
          #pragma unroll
          for (int j = 0; j < 4; j++)
            gsm[wm * 32 + mt * 16 + g * 4 + j][wn * 32 + nt * 16 + r] = accs[mt][nt][j];
    }
    __syncthreads();
    // elementwise cell update (c and x_proj in registers)
    float hnew[4];
    #pragma unroll
    for (int u = 0; u < 4; u++) {
      int hh = hh0 * 4 + u;
      float iv = gsm[b_loc][hh]      + xiv[u];
      float fv = gsm[b_loc][16 + hh] + xfv[u];
      float gv = gsm[b_loc][32 + hh] + xgv[u];
      float ov = gsm[b_loc][48 + hh] + xov[u];
      iv = 1.f / (1.f + __expf(-iv));
      fv = 1.f / (1.f + __expf(-fv));
      gv = 2.f / (1.f + __expf(-2.f * gv)) - 1.f;
      ov = 1.f / (1.f + __expf(-ov));
      float cn = fv * cvv[u] + iv * gv;
      cvv[u] = cn;
      float tc = 2.f / (1.f + __expf(-2.f * cn)) - 1.f;
      hnew[u] = ov * tc;
    }
    f16x4 hw; hw[0] = (f16)hnew[0]; hw[1] = (f16)hnew[1]; hw[2] = (f16)hnew[2]; hw[3] = (f16)hnew[3];
    *(f16x4*)(hob + (size_t)t * 262144) = hw;
    if (t + 1 < LSTM_T) group_barrier(bar, 64u * (unsigned)(t + 1));
  }
}

extern "C" void kernel_launch(void* const* d_in, const int* in_sizes, int n_in,
                              void* d_out, int out_size, void* d_ws, size_t ws_size,
                              hipStream_t stream)
{
  (void)in_sizes; (void)n_in; (void)out_size; (void)ws_size;
  const float* C     = (const float*)d_in[0];
  const float* W_ih  = (const float*)d_in[1];
  const float* W_hh  = (const float*)d_in[2];
  const float* b_ih  = (const float*)d_in[3];
  const float* b_hh  = (const float*)d_in[4];
  const float* W_lin = (const float*)d_in[5];
  const float* b_lin = (const float*)d_in[6];

  char* ws = (char*)d_ws;
  size_t off = 0;
  auto alloc = [&](size_t bytes) { void* p = ws + off; off += (bytes + 255) & ~(size_t)255; return p; };
  f16*      Wih16  = (f16*)alloc((size_t)GATES * LSTM_H * 2);
  f16*      Wlin16 = (f16*)alloc((size_t)LSTM_O * LSTM_H * 2);
  f16*      C16    = (f16*)alloc((size_t)LSTM_B * LSTM_H * 2);
  f16*      Wpack  = (f16*)alloc((size_t)GATES * LSTM_H * 2);
  float*    xp     = (float*)alloc((size_t)LSTM_B * GATES * 4);
  f16*      hist   = (f16*)alloc((size_t)LSTM_T * LSTM_B * LSTM_H * 2);
  unsigned* bars   = (unsigned*)alloc(4 * 256);

  cvt4_kernel<<<2048, 256, 0, stream>>>((const float4*)W_ih,  (f16x4*)Wih16,  GATES * LSTM_H / 4);
  cvt4_kernel<<<512,  256, 0, stream>>>((const float4*)W_lin, (f16x4*)Wlin16, LSTM_O * LSTM_H / 4);
  cvt4_kernel<<<256,  256, 0, stream>>>((const float4*)C,     (f16x4*)C16,    LSTM_B * LSTM_H / 4);
  pack_whh_kernel<<<2048, 256, 0, stream>>>(W_hh, Wpack);
  hipMemsetAsync(bars, 0, 4 * 256, stream);

  // x_proj = C @ W_ih^T + b_ih + b_hh (input constant across time)
  gemm_bt_kernel<<<(LSTM_B / 64) * (GATES / 64), 256, 0, stream>>>(
      C16, Wih16, b_ih, b_hh, xp, LSTM_B, GATES, LSTM_H, GATES / 64, 0, 0);

  // recurrence: one cooperative kernel, all 128 steps
  {
    const f16* wp = Wpack; const float* xpp = xp; f16* hp = hist; unsigned* bp = bars;
    void* args[] = { (void*)&wp, (void*)&xpp, (void*)&hp, (void*)&bp };
    hipLaunchCooperativeKernel((void*)lstm_persist_kernel, dim3(256), dim3(256), args, 0, stream);
  }

  // ys = hist @ W_lin^T + b_lin, one batched GEMM over blocked hist
  gemm_bt_kernel<<<(LSTM_T * LSTM_B / 64) * (LSTM_O / 64), 256, 0, stream>>>(
      hist, Wlin16, b_lin, nullptr, (float*)d_out,
      LSTM_T * LSTM_B, LSTM_O, LSTM_H, LSTM_O / 64, 1, 1);
}

// Round 4
// 1404.118 us; speedup vs baseline: 2.0359x; 1.6553x over previous
//
#include <hip/hip_runtime.h>

typedef _Float16 f16;
typedef _Float16 f16x4 __attribute__((ext_vector_type(4)));
typedef _Float16 f16x8 __attribute__((ext_vector_type(8)));
typedef float f32x2 __attribute__((ext_vector_type(2)));
typedef float f32x4 __attribute__((ext_vector_type(4)));

#define LSTM_B 256
#define LSTM_H 1024
#define LSTM_O 512
#define LSTM_T 128
#define GATES 4096

// hist blocked layout: element (t, b, h) at
//   ((t*64 + (h>>4))*4 + (b>>6))*1024 + (b&63)*16 + (h&15)
// -> each producer WG writes ONE contiguous 2KB block per step.

// ---------------- fp32 -> fp16 convert (vectorized) ----------------
__global__ void cvt4_kernel(const float4* __restrict__ src, f16x4* __restrict__ dst, int n4) {
  int i = blockIdx.x * blockDim.x + threadIdx.x;
  int st = gridDim.x * blockDim.x;
  for (; i < n4; i += st) {
    float4 v = src[i];
    f16x4 o; o[0] = (f16)v.x; o[1] = (f16)v.y; o[2] = (f16)v.z; o[3] = (f16)v.w;
    dst[i] = o;
  }
}

// ---------------- pack Whh into fragment-linear f16 layout ----------------
__global__ void pack_whh_kernel(const float* __restrict__ Whh, f16* __restrict__ Wpack) {
  int idx = blockIdx.x * 256 + threadIdx.x;      // 64*128*64 = 524288 threads
  int lane = idx & 63;
  int f = (idx >> 6) & 127;
  int hj = idx >> 13;
  int kc = f >> 3, s = (f >> 2) & 1, wn = (f >> 1) & 1, nt = f & 1;
  int c = wn * 32 + nt * 16 + (lane & 15);
  int row = (c >> 4) * 1024 + hj * 16 + (c & 15);
  int k0 = kc * 64 + s * 32 + (lane >> 4) * 8;
  const float* src = Whh + (size_t)row * LSTM_H + k0;
  float4 v0 = *(const float4*)src;
  float4 v1 = *(const float4*)(src + 4);
  f16x8 o;
  o[0] = (f16)v0.x; o[1] = (f16)v0.y; o[2] = (f16)v0.z; o[3] = (f16)v0.w;
  o[4] = (f16)v1.x; o[5] = (f16)v1.y; o[6] = (f16)v1.z; o[7] = (f16)v1.w;
  *(f16x8*)(Wpack + (size_t)idx * 8) = o;
}

// ---------------- generic C[M,N] = A[MxK] * Bw[NxK]^T + bias ----------------
__global__ __launch_bounds__(256) void gemm_bt_kernel(
    const f16* __restrict__ A, const f16* __restrict__ Bw,
    const float* __restrict__ bias0, const float* __restrict__ bias1,
    float* __restrict__ out, int M, int N, int K, int gn, int xswz, int blkA)
{
  __shared__ __align__(16) f16 As[64][72];
  __shared__ __align__(16) f16 Bs[64][72];
  int bx = blockIdx.x;
  if (xswz) { int n = gridDim.x; bx = (bx & 7) * (n >> 3) + (bx >> 3); }  // bijective: n%8==0
  int mb = bx / gn;
  int m0 = mb * 64;
  int n0 = (bx - mb * gn) * 64;
  int tid = threadIdx.x;
  int lane = tid & 63, w = tid >> 6;
  int wm = w >> 1, wn = w & 1;
  int sr = tid >> 2, sseg = tid & 3;
  const f16* ga;
  size_t kadv;
  if (blkA) {
    int m = m0 + sr;
    ga = A + ((size_t)(m >> 8) * 256 + (size_t)sseg * 4 + ((m >> 6) & 3)) * 1024 + (m & 63) * 16;
    kadv = 16384;
  } else {
    ga = A + (size_t)(m0 + sr) * K + sseg * 16;
    kadv = 64;
  }
  const f16* gb = Bw + (size_t)(n0 + sr) * K + sseg * 16;
  f32x4 acc00 = {}, acc01 = {}, acc10 = {}, acc11 = {};
  f16x8 ra0 = *(const f16x8*)ga, ra1 = *(const f16x8*)(ga + 8);
  f16x8 rb0 = *(const f16x8*)gb, rb1 = *(const f16x8*)(gb + 8);
  for (int kc = 0; kc < K; kc += 64) {
    __syncthreads();
    *(f16x8*)&As[sr][sseg * 16]     = ra0;
    *(f16x8*)&As[sr][sseg * 16 + 8] = ra1;
    *(f16x8*)&Bs[sr][sseg * 16]     = rb0;
    *(f16x8*)&Bs[sr][sseg * 16 + 8] = rb1;
    __syncthreads();
    if (kc + 64 < K) {
      ga += kadv; gb += 64;
      ra0 = *(const f16x8*)ga; ra1 = *(const f16x8*)(ga + 8);
      rb0 = *(const f16x8*)gb; rb1 = *(const f16x8*)(gb + 8);
    }
    int g = lane >> 4, r = lane & 15;
    #pragma unroll
    for (int s = 0; s < 2; s++) {
      f16x8 a0 = *(const f16x8*)&As[wm * 32      + r][s * 32 + g * 8];
      f16x8 a1 = *(const f16x8*)&As[wm * 32 + 16 + r][s * 32 + g * 8];
      f16x8 b0 = *(const f16x8*)&Bs[wn * 32      + r][s * 32 + g * 8];
      f16x8 b1 = *(const f16x8*)&Bs[wn * 32 + 16 + r][s * 32 + g * 8];
      acc00 = __builtin_amdgcn_mfma_f32_16x16x32_f16(a0, b0, acc00, 0, 0, 0);
      acc01 = __builtin_amdgcn_mfma_f32_16x16x32_f16(a0, b1, acc01, 0, 0, 0);
      acc10 = __builtin_amdgcn_mfma_f32_16x16x32_f16(a1, b0, acc10, 0, 0, 0);
      acc11 = __builtin_amdgcn_mfma_f32_16x16x32_f16(a1, b1, acc11, 0, 0, 0);
    }
  }
  int gq = lane >> 4, rr = lane & 15;
  f32x4 accs[2][2] = {{acc00, acc01}, {acc10, acc11}};
  #pragma unroll
  for (int mt = 0; mt < 2; mt++)
    #pragma unroll
    for (int nt = 0; nt < 2; nt++) {
      int row = m0 + wm * 32 + mt * 16 + gq * 4;
      int col = n0 + wn * 32 + nt * 16 + rr;
      float bv = bias0 ? bias0[col] : 0.f;
      if (bias1) bv += bias1[col];
      #pragma unroll
      for (int j = 0; j < 4; j++)
        out[(size_t)(row + j) * N + col] = accs[mt][nt][j] + bv;
    }
}

// ---------------- persistent LSTM recurrence ----------------
// Sync design (fence-light):
//  - h stores are write-through to the coherence point (sc0 sc1): no dirty L2,
//    so NO release fence (no buffer_wbl2) is ever needed.
//  - per-wave s_waitcnt vmcnt(0) + __syncthreads -> all WG stores at LLC.
//  - thread0: relaxed agent atomicAdd + relaxed agent poll (monotonic counter).
//  - thread0-only acquire fence (s_waitcnt + buffer_inv): invalidates this CU's
//    L1 + XCD L2 so next step's hist reads refill from LLC. 1 inv/WG/step.
__global__ __launch_bounds__(256, 1) void lstm_persist_kernel(
    const f16* __restrict__ Wpack, const float* __restrict__ xp,
    f16* __restrict__ hist, unsigned* __restrict__ bars)
{
  __shared__ __align__(16) f16 Bres[65536];      // 128 KB resident Whh frags
  __shared__ __align__(16) char smx[16640];      // A dbuf (2x8KB, XOR-swizzled) / gsm overlay

  char* Ab = smx;
  float (*gsm)[65] = (float(*)[65])smx;

  const int wg = blockIdx.x;
  const int mb = (wg & 7) >> 1;                        // XCD pair -> batch group
  const int hj = ((wg >> 3) << 1) | (wg & 1);          // 64 hid-slices per group
  unsigned* bar = bars + mb * 64;                      // 256B-spaced counters
  const int m0 = mb * 64;
  const int tid = threadIdx.x;
  const int lane = tid & 63, w = tid >> 6;
  const int wm = w >> 1, wn = w & 1;
  const int g = lane >> 4, r = lane & 15;

  // one-time: Whh fragment strip -> LDS
  {
    const f16x8* src = (const f16x8*)(Wpack + (size_t)hj * 65536);
    f16x8* dst = (f16x8*)Bres;
    for (int i = tid; i < 8192; i += 256) dst[i] = src[i];
  }

  // one-time: per-thread x_proj and c registers
  const int b_loc = tid & 63, hh0 = tid >> 6;
  const float* xprow = xp + (size_t)(m0 + b_loc) * GATES + hj * 16 + hh0 * 4;
  float4 xi = *(const float4*)(xprow);
  float4 xf = *(const float4*)(xprow + LSTM_H);
  float4 xg = *(const float4*)(xprow + 2 * LSTM_H);
  float4 xo = *(const float4*)(xprow + 3 * LSTM_H);
  float xiv[4] = {xi.x, xi.y, xi.z, xi.w};
  float xfv[4] = {xf.x, xf.y, xf.z, xf.w};
  float xgv[4] = {xg.x, xg.y, xg.z, xg.w};
  float xov[4] = {xo.x, xo.y, xo.z, xo.w};
  float cvv[4] = {0.f, 0.f, 0.f, 0.f};

  // staging geometry (A tile 64b x 64k, XOR-swizzled rows)
  const int sr = tid >> 2, sseg = tid & 3;
  const int wb0 = sr * 128 + ((sseg * 32)      ^ ((sr & 7) << 4));
  const int wb1 = sr * 128 + ((sseg * 32 + 16) ^ ((sr & 7) << 4));
  const int xr = (r & 7) << 4;
  const int rb00 = (wm * 32 + r) * 128 + ((g * 16)      ^ xr);
  const int rb01 = (wm * 32 + r) * 128 + ((64 + g * 16) ^ xr);
  const int rb10 = rb00 + 16 * 128;
  const int rb11 = rb01 + 16 * 128;
  const int bb = wn * 2048 + lane * 16;
  const int stag = hj >> 2;                            // staggered K-chunk start
  const f16* tb_base = hist + (size_t)sseg * 4096 + (size_t)mb * 1024 + sr * 16;
  f16* hob = hist + ((size_t)hj * 4 + mb) * 1024 + b_loc * 16 + hh0 * 4;

  __syncthreads();   // Bres ready

  for (int t = 0; t < LSTM_T; t++) {
    f32x4 acc00 = {}, acc01 = {}, acc10 = {}, acc11 = {};
    if (t > 0) {
      const f16* tb = tb_base + (size_t)(t - 1) * 262144;
      f16x8 ra0 = *(const f16x8*)(tb + stag * 16384);
      f16x8 ra1 = *(const f16x8*)(tb + stag * 16384 + 8);
      *(f16x8*)(Ab + wb0) = ra0;
      *(f16x8*)(Ab + wb1) = ra1;
      {
        int k1 = (stag + 1) & 15;
        ra0 = *(const f16x8*)(tb + k1 * 16384);
        ra1 = *(const f16x8*)(tb + k1 * 16384 + 8);
      }
      __syncthreads();
      #pragma unroll 2
      for (int i = 0; i < 16; i++) {
        const int bo = (i & 1) * 8192;
        const int kc = (i + stag) & 15;
        f16x8 rn0 = {}, rn1 = {};
        if (i + 2 < 16) {
          int k2 = (i + 2 + stag) & 15;
          rn0 = *(const f16x8*)(tb + k2 * 16384);
          rn1 = *(const f16x8*)(tb + k2 * 16384 + 8);
        }
        const char* Bb = (const char*)Bres + kc * 8192;
        f16x8 a00 = *(const f16x8*)(Ab + bo + rb00);
        f16x8 a10 = *(const f16x8*)(Ab + bo + rb10);
        f16x8 b00 = *(const f16x8*)(Bb + bb);
        f16x8 b10 = *(const f16x8*)(Bb + bb + 1024);
        acc00 = __builtin_amdgcn_mfma_f32_16x16x32_f16(a00, b00, acc00, 0, 0, 0);
        acc01 = __builtin_amdgcn_mfma_f32_16x16x32_f16(a00, b10, acc01, 0, 0, 0);
        acc10 = __builtin_amdgcn_mfma_f32_16x16x32_f16(a10, b00, acc10, 0, 0, 0);
        acc11 = __builtin_amdgcn_mfma_f32_16x16x32_f16(a10, b10, acc11, 0, 0, 0);
        f16x8 a01 = *(const f16x8*)(Ab + bo + rb01);
        f16x8 a11 = *(const f16x8*)(Ab + bo + rb11);
        f16x8 b01 = *(const f16x8*)(Bb + 4096 + bb);
        f16x8 b11 = *(const f16x8*)(Bb + 4096 + bb + 1024);
        acc00 = __builtin_amdgcn_mfma_f32_16x16x32_f16(a01, b01, acc00, 0, 0, 0);
        acc01 = __builtin_amdgcn_mfma_f32_16x16x32_f16(a01, b11, acc01, 0, 0, 0);
        acc10 = __builtin_amdgcn_mfma_f32_16x16x32_f16(a11, b01, acc10, 0, 0, 0);
        acc11 = __builtin_amdgcn_mfma_f32_16x16x32_f16(a11, b11, acc11, 0, 0, 0);
        if (i + 1 < 16) {
          *(f16x8*)(Ab + (bo ^ 8192) + wb0) = ra0;
          *(f16x8*)(Ab + (bo ^ 8192) + wb1) = ra1;
          ra0 = rn0; ra1 = rn1;
        }
        __syncthreads();
      }
    }
    // gates tile -> gsm overlay
    {
      f32x4 accs[2][2] = {{acc00, acc01}, {acc10, acc11}};
      #pragma unroll
      for (int mt = 0; mt < 2; mt++)
        #pragma unroll
        for (int nt = 0; nt < 2; nt++)
          #pragma unroll
          for (int j = 0; j < 4; j++)
            gsm[wm * 32 + mt * 16 + g * 4 + j][wn * 32 + nt * 16 + r] = accs[mt][nt][j];
    }
    __syncthreads();
    // elementwise cell update (c and x_proj in registers)
    float hnew[4];
    #pragma unroll
    for (int u = 0; u < 4; u++) {
      int hh = hh0 * 4 + u;
      float iv = gsm[b_loc][hh]      + xiv[u];
      float fv = gsm[b_loc][16 + hh] + xfv[u];
      float gv = gsm[b_loc][32 + hh] + xgv[u];
      float ov = gsm[b_loc][48 + hh] + xov[u];
      iv = 1.f / (1.f + __expf(-iv));
      fv = 1.f / (1.f + __expf(-fv));
      gv = 2.f / (1.f + __expf(-2.f * gv)) - 1.f;
      ov = 1.f / (1.f + __expf(-ov));
      float cn = fv * cvv[u] + iv * gv;
      cvv[u] = cn;
      float tc = 2.f / (1.f + __expf(-2.f * cn)) - 1.f;
      hnew[u] = ov * tc;
    }
    f16x4 hw; hw[0] = (f16)hnew[0]; hw[1] = (f16)hnew[1]; hw[2] = (f16)hnew[2]; hw[3] = (f16)hnew[3];
    // write-through store (sc0 sc1): coherent at LLC, leaves no dirty L2 line
    {
      union { f16x4 h; f32x2 f2; } hu; hu.h = hw;
      f16* haddr = hob + (size_t)t * 262144;
      asm volatile("global_store_dwordx2 %0, %1, off sc0 sc1" :: "v"(haddr), "v"(hu.f2) : "memory");
    }
    if (t + 1 < LSTM_T) {
      asm volatile("s_waitcnt vmcnt(0)" ::: "memory");   // this wave's h-store at LLC
      __syncthreads();                                    // all waves of WG drained
      if (tid == 0) {
        __hip_atomic_fetch_add(bar, 1u, __ATOMIC_RELAXED, __HIP_MEMORY_SCOPE_AGENT);
        unsigned target = 64u * (unsigned)(t + 1);
        while (__hip_atomic_load(bar, __ATOMIC_RELAXED, __HIP_MEMORY_SCOPE_AGENT) < target)
          __builtin_amdgcn_s_sleep(1);
        // one acquire fence per WG: s_waitcnt + buffer_inv (L1+L2 of this CU/XCD)
        __builtin_amdgcn_fence(__ATOMIC_ACQUIRE, "agent");
      }
      __syncthreads();
    }
  }
}

extern "C" void kernel_launch(void* const* d_in, const int* in_sizes, int n_in,
                              void* d_out, int out_size, void* d_ws, size_t ws_size,
                              hipStream_t stream)
{
  (void)in_sizes; (void)n_in; (void)out_size; (void)ws_size;
  const float* C     = (const float*)d_in[0];
  const float* W_ih  = (const float*)d_in[1];
  const float* W_hh  = (const float*)d_in[2];
  const float* b_ih  = (const float*)d_in[3];
  const float* b_hh  = (const float*)d_in[4];
  const float* W_lin = (const float*)d_in[5];
  const float* b_lin = (const float*)d_in[6];

  char* ws = (char*)d_ws;
  size_t off = 0;
  auto alloc = [&](size_t bytes) { void* p = ws + off; off += (bytes + 255) & ~(size_t)255; return p; };
  f16*      Wih16  = (f16*)alloc((size_t)GATES * LSTM_H * 2);
  f16*      Wlin16 = (f16*)alloc((size_t)LSTM_O * LSTM_H * 2);
  f16*      C16    = (f16*)alloc((size_t)LSTM_B * LSTM_H * 2);
  f16*      Wpack  = (f16*)alloc((size_t)GATES * LSTM_H * 2);
  float*    xp     = (float*)alloc((size_t)LSTM_B * GATES * 4);
  f16*      hist   = (f16*)alloc((size_t)LSTM_T * LSTM_B * LSTM_H * 2);
  unsigned* bars   = (unsigned*)alloc(4 * 256);

  cvt4_kernel<<<2048, 256, 0, stream>>>((const float4*)W_ih,  (f16x4*)Wih16,  GATES * LSTM_H / 4);
  cvt4_kernel<<<512,  256, 0, stream>>>((const float4*)W_lin, (f16x4*)Wlin16, LSTM_O * LSTM_H / 4);
  cvt4_kernel<<<256,  256, 0, stream>>>((const float4*)C,     (f16x4*)C16,    LSTM_B * LSTM_H / 4);
  pack_whh_kernel<<<2048, 256, 0, stream>>>(W_hh, Wpack);
  hipMemsetAsync(bars, 0, 4 * 256, stream);

  // x_proj = C @ W_ih^T + b_ih + b_hh (input constant across time)
  gemm_bt_kernel<<<(LSTM_B / 64) * (GATES / 64), 256, 0, stream>>>(
      C16, Wih16, b_ih, b_hh, xp, LSTM_B, GATES, LSTM_H, GATES / 64, 0, 0);

  // recurrence: one cooperative kernel, all 128 steps
  {
    const f16* wp = Wpack; const float* xpp = xp; f16* hp = hist; unsigned* bp = bars;
    void* args[] = { (void*)&wp, (void*)&xpp, (void*)&hp, (void*)&bp };
    hipLaunchCooperativeKernel((void*)lstm_persist_kernel, dim3(256), dim3(256), args, 0, stream);
  }

  // ys = hist @ W_lin^T + b_lin, one batched GEMM over blocked hist
  gemm_bt_kernel<<<(LSTM_T * LSTM_B / 64) * (LSTM_O / 64), 256, 0, stream>>>(
      hist, Wlin16, b_lin, nullptr, (float*)d_out,
      LSTM_T * LSTM_B, LSTM_O, LSTM_H, LSTM_O / 64, 1, 1);
}

// Round 5
// 930.516 us; speedup vs baseline: 3.0721x; 1.5090x over previous
//
#include <hip/hip_runtime.h>

typedef _Float16 f16;
typedef _Float16 f16x4 __attribute__((ext_vector_type(4)));
typedef _Float16 f16x8 __attribute__((ext_vector_type(8)));
typedef float f32x2 __attribute__((ext_vector_type(2)));
typedef float f32x4 __attribute__((ext_vector_type(4)));

#define LSTM_B 256
#define LSTM_H 1024
#define LSTM_O 512
#define LSTM_T 128
#define GATES 4096

// hist blocked layout: element (t, b, h) at
//   ((t*64 + (h>>4))*4 + (b>>6))*1024 + (b&63)*16 + (h&15)
// -> producer WG writes ONE contiguous 2KB block per step, and consumer MFMA
//    A-fragments are directly loadable: a wave's lanes 0-31 cover one
//    contiguous 512B span, lanes 32-63 the next block's span (coalesced).

// ---------------- fp32 -> fp16 convert (vectorized) ----------------
__global__ void cvt4_kernel(const float4* __restrict__ src, f16x4* __restrict__ dst, int n4) {
  int i = blockIdx.x * blockDim.x + threadIdx.x;
  int st = gridDim.x * blockDim.x;
  for (; i < n4; i += st) {
    float4 v = src[i];
    f16x4 o; o[0] = (f16)v.x; o[1] = (f16)v.y; o[2] = (f16)v.z; o[3] = (f16)v.w;
    dst[i] = o;
  }
}

// ---------------- pack Whh into fragment-linear f16 layout ----------------
__global__ void pack_whh_kernel(const float* __restrict__ Whh, f16* __restrict__ Wpack) {
  int idx = blockIdx.x * 256 + threadIdx.x;      // 64*128*64 = 524288 threads
  int lane = idx & 63;
  int f = (idx >> 6) & 127;
  int hj = idx >> 13;
  int kc = f >> 3, s = (f >> 2) & 1, wn = (f >> 1) & 1, nt = f & 1;
  int c = wn * 32 + nt * 16 + (lane & 15);
  int row = (c >> 4) * 1024 + hj * 16 + (c & 15);
  int k0 = kc * 64 + s * 32 + (lane >> 4) * 8;
  const float* src = Whh + (size_t)row * LSTM_H + k0;
  float4 v0 = *(const float4*)src;
  float4 v1 = *(const float4*)(src + 4);
  f16x8 o;
  o[0] = (f16)v0.x; o[1] = (f16)v0.y; o[2] = (f16)v0.z; o[3] = (f16)v0.w;
  o[4] = (f16)v1.x; o[5] = (f16)v1.y; o[6] = (f16)v1.z; o[7] = (f16)v1.w;
  *(f16x8*)(Wpack + (size_t)idx * 8) = o;
}

// ---------------- generic C[M,N] = A[MxK] * Bw[NxK]^T + bias ----------------
__global__ __launch_bounds__(256) void gemm_bt_kernel(
    const f16* __restrict__ A, const f16* __restrict__ Bw,
    const float* __restrict__ bias0, const float* __restrict__ bias1,
    float* __restrict__ out, int M, int N, int K, int gn, int xswz, int blkA)
{
  __shared__ __align__(16) f16 As[64][72];
  __shared__ __align__(16) f16 Bs[64][72];
  int bx = blockIdx.x;
  if (xswz) { int n = gridDim.x; bx = (bx & 7) * (n >> 3) + (bx >> 3); }  // bijective: n%8==0
  int mb = bx / gn;
  int m0 = mb * 64;
  int n0 = (bx - mb * gn) * 64;
  int tid = threadIdx.x;
  int lane = tid & 63, w = tid >> 6;
  int wm = w >> 1, wn = w & 1;
  int sr = tid >> 2, sseg = tid & 3;
  const f16* ga;
  size_t kadv;
  if (blkA) {
    int m = m0 + sr;
    ga = A + ((size_t)(m >> 8) * 256 + (size_t)sseg * 4 + ((m >> 6) & 3)) * 1024 + (m & 63) * 16;
    kadv = 16384;
  } else {
    ga = A + (size_t)(m0 + sr) * K + sseg * 16;
    kadv = 64;
  }
  const f16* gb = Bw + (size_t)(n0 + sr) * K + sseg * 16;
  f32x4 acc00 = {}, acc01 = {}, acc10 = {}, acc11 = {};
  f16x8 ra0 = *(const f16x8*)ga, ra1 = *(const f16x8*)(ga + 8);
  f16x8 rb0 = *(const f16x8*)gb, rb1 = *(const f16x8*)(gb + 8);
  for (int kc = 0; kc < K; kc += 64) {
    __syncthreads();
    *(f16x8*)&As[sr][sseg * 16]     = ra0;
    *(f16x8*)&As[sr][sseg * 16 + 8] = ra1;
    *(f16x8*)&Bs[sr][sseg * 16]     = rb0;
    *(f16x8*)&Bs[sr][sseg * 16 + 8] = rb1;
    __syncthreads();
    if (kc + 64 < K) {
      ga += kadv; gb += 64;
      ra0 = *(const f16x8*)ga; ra1 = *(const f16x8*)(ga + 8);
      rb0 = *(const f16x8*)gb; rb1 = *(const f16x8*)(gb + 8);
    }
    int g = lane >> 4, r = lane & 15;
    #pragma unroll
    for (int s = 0; s < 2; s++) {
      f16x8 a0 = *(const f16x8*)&As[wm * 32      + r][s * 32 + g * 8];
      f16x8 a1 = *(const f16x8*)&As[wm * 32 + 16 + r][s * 32 + g * 8];
      f16x8 b0 = *(const f16x8*)&Bs[wn * 32      + r][s * 32 + g * 8];
      f16x8 b1 = *(const f16x8*)&Bs[wn * 32 + 16 + r][s * 32 + g * 8];
      acc00 = __builtin_amdgcn_mfma_f32_16x16x32_f16(a0, b0, acc00, 0, 0, 0);
      acc01 = __builtin_amdgcn_mfma_f32_16x16x32_f16(a0, b1, acc01, 0, 0, 0);
      acc10 = __builtin_amdgcn_mfma_f32_16x16x32_f16(a1, b0, acc10, 0, 0, 0);
      acc11 = __builtin_amdgcn_mfma_f32_16x16x32_f16(a1, b1, acc11, 0, 0, 0);
    }
  }
  int gq = lane >> 4, rr = lane & 15;
  f32x4 accs[2][2] = {{acc00, acc01}, {acc10, acc11}};
  #pragma unroll
  for (int mt = 0; mt < 2; mt++)
    #pragma unroll
    for (int nt = 0; nt < 2; nt++) {
      int row = m0 + wm * 32 + mt * 16 + gq * 4;
      int col = n0 + wn * 32 + nt * 16 + rr;
      float bv = bias0 ? bias0[col] : 0.f;
      if (bias1) bv += bias1[col];
      #pragma unroll
      for (int j = 0; j < 4; j++)
        out[(size_t)(row + j) * N + col] = accs[mt][nt][j] + bv;
    }
}

// ---------------- persistent LSTM recurrence (dataflow-synced) ----------------
// ready[((t*4+mb)*16+kc)*16]: producers (hj = 4kc..4kc+3) each add 1 after their
// h-block store has drained to LLC (sc0 sc1 + vmcnt(0)). Consumers poll ==4 with
// relaxed agent loads (LLC-coherent), then load A-fragments straight from global.
// No group barrier, no fences, no LDS staging for A, no syncthreads in K-loop.
__device__ __forceinline__ void wait_chunk(const unsigned* p) {
  while (__hip_atomic_load(p, __ATOMIC_RELAXED, __HIP_MEMORY_SCOPE_AGENT) < 4u)
    __builtin_amdgcn_s_sleep(2);
  asm volatile("" ::: "memory");   // block hoisting of A-loads above the flag
}

__global__ __launch_bounds__(256, 1) void lstm_persist_kernel(
    const f16* __restrict__ Wpack, const float* __restrict__ xp,
    f16* __restrict__ hist, unsigned* __restrict__ ready)
{
  __shared__ __align__(16) f16 Bres[65536];      // 128 KB resident Whh frags
  __shared__ float gsm[64][65];                  // gate exchange

  const int wg = blockIdx.x;
  const int mb = (wg & 7) >> 1;                        // XCD pair -> batch group
  const int hj = ((wg >> 3) << 1) | (wg & 1);          // 64 hid-slices per group
  const int m0 = mb * 64;
  const int tid = threadIdx.x;
  const int lane = tid & 63, w = tid >> 6;
  const int wm = w >> 1, wn = w & 1;
  const int g = lane >> 4, r = lane & 15;

  // one-time: Whh fragment strip -> LDS
  {
    const f16x8* src = (const f16x8*)(Wpack + (size_t)hj * 65536);
    f16x8* dst = (f16x8*)Bres;
    for (int i = tid; i < 8192; i += 256) dst[i] = src[i];
  }

  // one-time: per-thread x_proj and c registers
  const int b_loc = tid & 63, hh0 = tid >> 6;
  const float* xprow = xp + (size_t)(m0 + b_loc) * GATES + hj * 16 + hh0 * 4;
  float4 xi = *(const float4*)(xprow);
  float4 xf = *(const float4*)(xprow + LSTM_H);
  float4 xg = *(const float4*)(xprow + 2 * LSTM_H);
  float4 xo = *(const float4*)(xprow + 3 * LSTM_H);
  float xiv[4] = {xi.x, xi.y, xi.z, xi.w};
  float xfv[4] = {xf.x, xf.y, xf.z, xf.w};
  float xgv[4] = {xg.x, xg.y, xg.z, xg.w};
  float xov[4] = {xo.x, xo.y, xo.z, xo.w};
  float cvv[4] = {0.f, 0.f, 0.f, 0.f};

  // A-fragment invariant offset (f16 units) within a timestep slab:
  //   addr = t*262144 + kc*16384 + s*8192 + mt*256 + inv
  const int inv = (g >> 1) * 4096 + mb * 1024 + wm * 512 + r * 16 + (g & 1) * 8;
  const int stag = hj >> 2;                            // start at own chunk
  const int bbo = wn * 2048 + lane * 16;               // B frag byte offset base
  f16* hob = hist + ((size_t)hj * 4 + mb) * 1024 + b_loc * 16 + hh0 * 4;
  unsigned* myflag = ready + (size_t)mb * 256 + (size_t)(hj >> 2) * 16;

  __syncthreads();   // Bres ready

  for (int t = 0; t < LSTM_T; t++) {
    f32x4 acc00 = {}, acc01 = {}, acc10 = {}, acc11 = {};
    if (t > 0) {
      const f16* hb = hist + (size_t)(t - 1) * 262144 + inv;
      const unsigned* rdt = ready + (size_t)(t - 1) * 1024 + (size_t)mb * 256;
      f16x8 sA[3][4];
      // 3-stage prologue
      #pragma unroll
      for (int j = 0; j < 3; j++) {
        const int kc = (stag + j) & 15;
        wait_chunk(rdt + kc * 16);
        const f16* p = hb + kc * 16384;
        sA[j][0] = *(const f16x8*)(p);
        sA[j][1] = *(const f16x8*)(p + 256);
        sA[j][2] = *(const f16x8*)(p + 8192);
        sA[j][3] = *(const f16x8*)(p + 8448);
      }
      #pragma unroll
      for (int i = 0; i < 16; i++) {
        const int kc = (stag + i) & 15;
        const int st = i % 3;
        const char* Bb = (const char*)Bres + kc * 8192;
        f16x8 b00 = *(const f16x8*)(Bb + bbo);
        f16x8 b10 = *(const f16x8*)(Bb + bbo + 1024);
        f16x8 b01 = *(const f16x8*)(Bb + 4096 + bbo);
        f16x8 b11 = *(const f16x8*)(Bb + 4096 + bbo + 1024);
        acc00 = __builtin_amdgcn_mfma_f32_16x16x32_f16(sA[st][0], b00, acc00, 0, 0, 0);
        acc01 = __builtin_amdgcn_mfma_f32_16x16x32_f16(sA[st][0], b10, acc01, 0, 0, 0);
        acc10 = __builtin_amdgcn_mfma_f32_16x16x32_f16(sA[st][1], b00, acc10, 0, 0, 0);
        acc11 = __builtin_amdgcn_mfma_f32_16x16x32_f16(sA[st][1], b10, acc11, 0, 0, 0);
        acc00 = __builtin_amdgcn_mfma_f32_16x16x32_f16(sA[st][2], b01, acc00, 0, 0, 0);
        acc01 = __builtin_amdgcn_mfma_f32_16x16x32_f16(sA[st][2], b11, acc01, 0, 0, 0);
        acc10 = __builtin_amdgcn_mfma_f32_16x16x32_f16(sA[st][3], b01, acc10, 0, 0, 0);
        acc11 = __builtin_amdgcn_mfma_f32_16x16x32_f16(sA[st][3], b11, acc11, 0, 0, 0);
        if (i + 3 < 16) {                       // refill stage with chunk i+3
          const int kn = (stag + i + 3) & 15;
          wait_chunk(rdt + kn * 16);
          const f16* p = hb + kn * 16384;
          sA[st][0] = *(const f16x8*)(p);
          sA[st][1] = *(const f16x8*)(p + 256);
          sA[st][2] = *(const f16x8*)(p + 8192);
          sA[st][3] = *(const f16x8*)(p + 8448);
        }
      }
    }
    // gates tile -> gsm
    {
      f32x4 accs[2][2] = {{acc00, acc01}, {acc10, acc11}};
      #pragma unroll
      for (int mt = 0; mt < 2; mt++)
        #pragma unroll
        for (int nt = 0; nt < 2; nt++)
          #pragma unroll
          for (int j = 0; j < 4; j++)
            gsm[wm * 32 + mt * 16 + g * 4 + j][wn * 32 + nt * 16 + r] = accs[mt][nt][j];
    }
    __syncthreads();
    // elementwise cell update (c and x_proj in registers)
    float hnew[4];
    #pragma unroll
    for (int u = 0; u < 4; u++) {
      int hh = hh0 * 4 + u;
      float iv = gsm[b_loc][hh]      + xiv[u];
      float fv = gsm[b_loc][16 + hh] + xfv[u];
      float gv = gsm[b_loc][32 + hh] + xgv[u];
      float ov = gsm[b_loc][48 + hh] + xov[u];
      iv = 1.f / (1.f + __expf(-iv));
      fv = 1.f / (1.f + __expf(-fv));
      gv = 2.f / (1.f + __expf(-2.f * gv)) - 1.f;
      ov = 1.f / (1.f + __expf(-ov));
      float cn = fv * cvv[u] + iv * gv;
      cvv[u] = cn;
      float tc = 2.f / (1.f + __expf(-2.f * cn)) - 1.f;
      hnew[u] = ov * tc;
    }
    f16x4 hw; hw[0] = (f16)hnew[0]; hw[1] = (f16)hnew[1]; hw[2] = (f16)hnew[2]; hw[3] = (f16)hnew[3];
    // write-through store (sc0 sc1): coherent at LLC, no dirty L2 line
    {
      union { f16x4 h; f32x2 f2; } hu; hu.h = hw;
      f16* haddr = hob + (size_t)t * 262144;
      asm volatile("global_store_dwordx2 %0, %1, off sc0 sc1" :: "v"(haddr), "v"(hu.f2) : "memory");
    }
    asm volatile("s_waitcnt vmcnt(0)" ::: "memory");   // this wave's h-store at LLC
    __syncthreads();                                   // all waves drained (+ gsm reads done)
    if (tid == 0)
      __hip_atomic_fetch_add(myflag + (size_t)t * 1024, 1u,
                             __ATOMIC_RELAXED, __HIP_MEMORY_SCOPE_AGENT);
  }
}

extern "C" void kernel_launch(void* const* d_in, const int* in_sizes, int n_in,
                              void* d_out, int out_size, void* d_ws, size_t ws_size,
                              hipStream_t stream)
{
  (void)in_sizes; (void)n_in; (void)out_size; (void)ws_size;
  const float* C     = (const float*)d_in[0];
  const float* W_ih  = (const float*)d_in[1];
  const float* W_hh  = (const float*)d_in[2];
  const float* b_ih  = (const float*)d_in[3];
  const float* b_hh  = (const float*)d_in[4];
  const float* W_lin = (const float*)d_in[5];
  const float* b_lin = (const float*)d_in[6];

  char* ws = (char*)d_ws;
  size_t off = 0;
  auto alloc = [&](size_t bytes) { void* p = ws + off; off += (bytes + 255) & ~(size_t)255; return p; };
  f16*      Wih16  = (f16*)alloc((size_t)GATES * LSTM_H * 2);
  f16*      Wlin16 = (f16*)alloc((size_t)LSTM_O * LSTM_H * 2);
  f16*      C16    = (f16*)alloc((size_t)LSTM_B * LSTM_H * 2);
  f16*      Wpack  = (f16*)alloc((size_t)GATES * LSTM_H * 2);
  float*    xp     = (float*)alloc((size_t)LSTM_B * GATES * 4);
  f16*      hist   = (f16*)alloc((size_t)LSTM_T * LSTM_B * LSTM_H * 2);
  unsigned* ready  = (unsigned*)alloc((size_t)LSTM_T * 1024 * 4);   // [t][mb][kc] 64B-spaced

  cvt4_kernel<<<2048, 256, 0, stream>>>((const float4*)W_ih,  (f16x4*)Wih16,  GATES * LSTM_H / 4);
  cvt4_kernel<<<512,  256, 0, stream>>>((const float4*)W_lin, (f16x4*)Wlin16, LSTM_O * LSTM_H / 4);
  cvt4_kernel<<<256,  256, 0, stream>>>((const float4*)C,     (f16x4*)C16,    LSTM_B * LSTM_H / 4);
  pack_whh_kernel<<<2048, 256, 0, stream>>>(W_hh, Wpack);
  hipMemsetAsync(ready, 0, (size_t)LSTM_T * 1024 * 4, stream);

  // x_proj = C @ W_ih^T + b_ih + b_hh (input constant across time)
  gemm_bt_kernel<<<(LSTM_B / 64) * (GATES / 64), 256, 0, stream>>>(
      C16, Wih16, b_ih, b_hh, xp, LSTM_B, GATES, LSTM_H, GATES / 64, 0, 0);

  // recurrence: one cooperative kernel, all 128 steps, dataflow-synced
  {
    const f16* wp = Wpack; const float* xpp = xp; f16* hp = hist; unsigned* rp = ready;
    void* args[] = { (void*)&wp, (void*)&xpp, (void*)&hp, (void*)&rp };
    hipLaunchCooperativeKernel((void*)lstm_persist_kernel, dim3(256), dim3(256), args, 0, stream);
  }

  // ys = hist @ W_lin^T + b_lin, one batched GEMM over blocked hist
  gemm_bt_kernel<<<(LSTM_T * LSTM_B / 64) * (LSTM_O / 64), 256, 0, stream>>>(
      hist, Wlin16, b_lin, nullptr, (float*)d_out,
      LSTM_T * LSTM_B, LSTM_O, LSTM_H, LSTM_O / 64, 1, 1);
}